// Round 14
// baseline (205.761 us; speedup 1.0000x reference)
//
#include <hip/hip_runtime.h>

#define NN 50000
#define NE 800000
#define DF 128
#define NG 64
#define NC 10
#define NBK 98            // ceil(NN/512) coarse buckets (dst>>9)
#define PART_CHUNK 4096
#define PART_GRID 196     // 196*4096 >= 800000
#define ACAP 12288        // arena capacity per bucket (avg 8163, max ~8600)
#define FINE_CAP 12288
#define RT 136            // h staging row stride (ushorts)
#define CAST_GRID 6250    // NN*DF/4/256
#define PREP_GRID (CAST_GRID + 32)
#define POOL_GRID 391     // ceil(ceil(NN/32)/4)

typedef short bf16x8 __attribute__((ext_vector_type(8)));
typedef float f32x4  __attribute__((ext_vector_type(4)));

__device__ __forceinline__ void atomAddF(float* p, float v) {
  __hip_atomic_fetch_add(p, v, __ATOMIC_RELAXED, __HIP_MEMORY_SCOPE_AGENT);
}
__device__ __forceinline__ float b2f(unsigned short u) {
  union { unsigned int i; float f; } v; v.i = (unsigned int)u << 16; return v.f;
}
__device__ __forceinline__ unsigned int f2b(float f) {
  unsigned int i = __float_as_uint(f);
  return (i + 0x7fffu + ((i >> 16) & 1u)) >> 16;
}

// ======== merged prep (cast x, weights->fragment-major) + edge partition ========
__global__ __launch_bounds__(256) void k_prep_part(const float* __restrict__ x,
                                                   unsigned short* __restrict__ xb,
                                                   const float* __restrict__ W0,
                                                   const float* __restrict__ W1,
                                                   const float* __restrict__ W2,
                                                   const float* __restrict__ W3,
                                                   unsigned short* __restrict__ Wt,
                                                   const int* __restrict__ src,
                                                   const int* __restrict__ dst,
                                                   int* __restrict__ cnt_b,
                                                   unsigned int* __restrict__ arena)
{
  __shared__ unsigned int stage[PART_CHUNK];
  __shared__ int lhist[128], lcnt[128], lcur[128], gbase[128];
  const int tid = threadIdx.x;
  const int b   = blockIdx.x;

  if (b < CAST_GRID) {
    const int i = b * 256 + tid;
    const float4 v = reinterpret_cast<const float4*>(x)[i];
    uint2 o;
    o.x = f2b(v.x) | (f2b(v.y) << 16);
    o.y = f2b(v.z) | (f2b(v.w) << 16);
    reinterpret_cast<uint2*>(xb)[i] = o;
    return;
  }
  if (b < PREP_GRID) {
    const int o = (b - CAST_GRID) * 256 + tid;
    const int mat = o >> 11;
    const float* W = (mat == 0) ? W0 : (mat == 1) ? W1 : (mat == 2) ? W2 : W3;
    const int rem = o & 2047;
    const int kb = rem >> 7, n = rem & 127;
    unsigned int u[8];
#pragma unroll
    for (int j = 0; j < 8; ++j) u[j] = f2b(W[(size_t)(kb * 8 + j) * DF + n]);
    uint4 p;
    p.x = u[0] | (u[1] << 16);
    p.y = u[2] | (u[3] << 16);
    p.z = u[4] | (u[5] << 16);
    p.w = u[6] | (u[7] << 16);
    *reinterpret_cast<uint4*>(Wt + (size_t)mat * DF * DF + (size_t)rem * 8) = p;
    return;
  }

  // ---- partition block ----
  const int vb = b - PREP_GRID;
  const int e0 = vb * PART_CHUNK;
  const int nE = min(PART_CHUNK, NE - e0);

  for (int i = tid; i < 128; i += 256) lhist[i] = 0;
  __syncthreads();
  unsigned int pk[16]; int bk[16];
#pragma unroll
  for (int i = 0; i < 16; ++i) {
    const int e = e0 + i * 256 + tid;
    if (e < NE) {
      const int d = dst[e], s = src[e];
      const int bb = d >> 9;
      bk[i] = bb;
      pk[i] = ((unsigned int)bb << 25) | ((unsigned int)(d & 511) << 16) | (unsigned int)s;
      atomicAdd(&lhist[bb], 1);
    } else bk[i] = -1;
  }
  __syncthreads();
  for (int i = tid; i < 128; i += 256) lcnt[i] = lhist[i];
  __syncthreads();
  for (int off = 1; off < 128; off <<= 1) {
    int v = 0;
    if (tid < 128 && tid >= off) v = lhist[tid - off];
    __syncthreads();
    if (tid < 128) lhist[tid] += v;
    __syncthreads();
  }
  if (tid < 128) lcur[tid] = lhist[tid] - lcnt[tid];
  __syncthreads();
#pragma unroll
  for (int i = 0; i < 16; ++i)
    if (bk[i] >= 0) {
      const int pos = atomicAdd(&lcur[bk[i]], 1);
      stage[pos] = pk[i];
    }
  __syncthreads();
  if (tid < NBK) {
    const int c = lcnt[tid];
    if (c > 0) gbase[tid] = atomicAdd(&cnt_b[tid], c);
  }
  __syncthreads();
  for (int idx = tid; idx < nE; idx += 256) {
    const unsigned int p = stage[idx];
    const int bb = (int)(p >> 25);
    const int loff = lhist[bb] - lcnt[bb];
    arena[(size_t)bb * ACAP + gbase[bb] + (idx - loff)] = p;
  }
}

// ---- per bucket: self-computed base + counting sort by (dstlocal, src>>13) ----
__global__ __launch_bounds__(256) void k_fine(const unsigned int* __restrict__ arena,
                                              const int* __restrict__ cnt_b,
                                              int* __restrict__ rs,
                                              unsigned short* __restrict__ es)
{
  __shared__ unsigned short les[FINE_CAP];   // 24 KB
  __shared__ int bins[4096];                 // 16 KB
  __shared__ int partials[256];
  __shared__ int basebuf[128];
  const int tid = threadIdx.x;
  const int b   = blockIdx.x;

  if (b == 0 && tid == 0) rs[NN] = NE;

  if (tid < 128) basebuf[tid] = (tid < NBK) ? cnt_b[tid] : 0;
  __syncthreads();
  for (int off = 1; off < 128; off <<= 1) {
    int u = 0;
    if (tid < 128 && tid >= off) u = basebuf[tid - off];
    __syncthreads();
    if (tid < 128) basebuf[tid] += u;
    __syncthreads();
  }
  const int wbase = (b == 0) ? 0 : basebuf[b - 1];
  const int cnt   = cnt_b[b];
  const int nbase = b << 9;
  const int nwin  = min(512, NN - nbase);
  const unsigned int* ap = arena + (size_t)b * ACAP;

  for (int i = tid; i < 4096; i += 256) bins[i] = 0;
  __syncthreads();
  for (int idx = tid; idx < cnt; idx += 256) {
    const unsigned int p = ap[idx];
    const int key = (int)(((p >> 16) & 511) << 3) | (int)((p & 0xffffu) >> 13);
    atomicAdd(&bins[key], 1);
  }
  __syncthreads();
  const int b16 = tid * 16;
  int sum = 0;
#pragma unroll
  for (int k = 0; k < 16; ++k) sum += bins[b16 + k];
  partials[tid] = sum;
  __syncthreads();
  for (int off = 1; off < 256; off <<= 1) {
    int u = (tid >= off) ? partials[tid - off] : 0;
    __syncthreads();
    partials[tid] += u;
    __syncthreads();
  }
  int run = partials[tid] - sum;
#pragma unroll
  for (int k = 0; k < 16; ++k) {
    const int v = bins[b16 + k];
    bins[b16 + k] = run;
    run += v;
  }
  __syncthreads();
  for (int i = tid; i < nwin; i += 256) rs[nbase + i] = wbase + bins[i << 3];
  __syncthreads();
  if (cnt <= FINE_CAP) {
    for (int idx = tid; idx < cnt; idx += 256) {
      const unsigned int p = ap[idx];
      const int key = (int)(((p >> 16) & 511) << 3) | (int)((p & 0xffffu) >> 13);
      const int pos = atomicAdd(&bins[key], 1);
      les[pos] = (unsigned short)(p & 0xffffu);
    }
    __syncthreads();
    for (int i = tid; i < cnt; i += 256) es[wbase + i] = les[i];
  } else {
    for (int idx = tid; idx < cnt; idx += 256) {
      const unsigned int p = ap[idx];
      const int key = (int)(((p >> 16) & 511) << 3) | (int)((p & 0xffffu) >> 13);
      const int pos = atomicAdd(&bins[key], 1);
      es[wbase + pos] = (unsigned short)(p & 0xffffu);
    }
  }
}

// ======== fused conv: gather(16 nodes/wave -> LDS) + double GEMM, no syncthreads ====
// out = relu(relu((feat+agg)@Wa+ba)@Wb+bb). Wave-private h buffer; weights from
// global (L1-resident fragment-major). 256 thr = 4 waves, 64 rows/block, grid 782.
__global__ __launch_bounds__(256, 4) void k_conv(const unsigned short* __restrict__ feat,
                                                 const int* __restrict__ rs,
                                                 const unsigned short* __restrict__ es,
                                                 const unsigned short* __restrict__ Wta,
                                                 const float* __restrict__ ba,
                                                 const unsigned short* __restrict__ Wtb,
                                                 const float* __restrict__ bb,
                                                 unsigned short* __restrict__ outb)
{
  __shared__ unsigned short hL[4][16 * RT];     // 17.4 KB
  const int tid  = threadIdx.x;
  const int lane = tid & 63;
  const int w    = tid >> 6;
  const int col  = lane & 15;
  const int kq   = lane >> 4;
  const int half = lane >> 5;
  const int l32  = lane & 31;
  const int offg = l32 * 4;

  unsigned short* hw = &hL[w][0];
  const int base = blockIdx.x * 64 + w * 16;

  // ---- phase 1: gather 16 nodes into hw (R12-proven pattern, 8 rows in flight) ----
  for (int r = 0; r < 16; ++r) {
    const int node = base + r;
    if (node >= NN) break;
    const int beg = rs[node];
    const int end = rs[node + 1];

    float a0 = 0.f, a1 = 0.f, a2 = 0.f, a3 = 0.f;
    if (!half) {
      const uint2 u = *reinterpret_cast<const uint2*>(feat + (size_t)node * DF + offg);
      a0 = b2f(u.x & 0xffff); a1 = b2f(u.x >> 16);
      a2 = b2f(u.y & 0xffff); a3 = b2f(u.y >> 16);
    }
    int j = beg;
    for (; j + 7 < end; j += 8) {
      const int i0 = es[j + half];
      const int i1 = es[j + 2 + half];
      const int i2 = es[j + 4 + half];
      const int i3 = es[j + 6 + half];
      const uint2 u0 = *reinterpret_cast<const uint2*>(feat + (size_t)i0 * DF + offg);
      const uint2 u1 = *reinterpret_cast<const uint2*>(feat + (size_t)i1 * DF + offg);
      const uint2 u2 = *reinterpret_cast<const uint2*>(feat + (size_t)i2 * DF + offg);
      const uint2 u3 = *reinterpret_cast<const uint2*>(feat + (size_t)i3 * DF + offg);
      a0 += b2f(u0.x & 0xffff) + b2f(u1.x & 0xffff) + b2f(u2.x & 0xffff) + b2f(u3.x & 0xffff);
      a1 += b2f(u0.x >> 16)    + b2f(u1.x >> 16)    + b2f(u2.x >> 16)    + b2f(u3.x >> 16);
      a2 += b2f(u0.y & 0xffff) + b2f(u1.y & 0xffff) + b2f(u2.y & 0xffff) + b2f(u3.y & 0xffff);
      a3 += b2f(u0.y >> 16)    + b2f(u1.y >> 16)    + b2f(u2.y >> 16)    + b2f(u3.y >> 16);
    }
    for (; j + 1 < end; j += 2) {
      const int i = es[j + half];
      const uint2 u = *reinterpret_cast<const uint2*>(feat + (size_t)i * DF + offg);
      a0 += b2f(u.x & 0xffff); a1 += b2f(u.x >> 16);
      a2 += b2f(u.y & 0xffff); a3 += b2f(u.y >> 16);
    }
    if (j < end && !half) {
      const int i = es[j];
      const uint2 u = *reinterpret_cast<const uint2*>(feat + (size_t)i * DF + offg);
      a0 += b2f(u.x & 0xffff); a1 += b2f(u.x >> 16);
      a2 += b2f(u.y & 0xffff); a3 += b2f(u.y >> 16);
    }
    a0 += __shfl_xor(a0, 32);
    a1 += __shfl_xor(a1, 32);
    a2 += __shfl_xor(a2, 32);
    a3 += __shfl_xor(a3, 32);
    if (!half) {
      uint2 o;
      o.x = f2b(a0) | (f2b(a1) << 16);
      o.y = f2b(a2) | (f2b(a3) << 16);
      *reinterpret_cast<uint2*>(&hw[r * RT + offg]) = o;
    }
  }
  // no barrier: hw is wave-private, LDS ops are in-order per wave

  // ---- phase 2: GEMM1 (B from LDS, Wa from global) ----
  bf16x8 bc[4];
#pragma unroll
  for (int s = 0; s < 4; ++s)
    bc[s] = *reinterpret_cast<const bf16x8*>(&hw[col * RT + s * 32 + kq * 8]);

  f32x4 acc[8];
#pragma unroll
  for (int nf = 0; nf < 8; ++nf) acc[nf] = (f32x4){0.f, 0.f, 0.f, 0.f};
#pragma unroll
  for (int s = 0; s < 4; ++s) {
#pragma unroll
    for (int nf = 0; nf < 8; ++nf) {
      const bf16x8 wa = *reinterpret_cast<const bf16x8*>(
          Wta + ((size_t)(s * 4 + kq) * 128 + nf * 16 + col) * 8);
      acc[nf] = __builtin_amdgcn_mfma_f32_16x16x32_bf16(wa, bc[s], acc[nf], 0, 0, 0);
    }
  }

  // ---- bias_a + relu -> bf16 -> hw (overwrite; per-wave in-order LDS) ----
#pragma unroll
  for (int nf = 0; nf < 8; ++nf) {
    const float4 bva = *reinterpret_cast<const float4*>(ba + nf * 16 + kq * 4);
    uint2 pk;
    pk.x = f2b(fmaxf(acc[nf][0] + bva.x, 0.f)) | (f2b(fmaxf(acc[nf][1] + bva.y, 0.f)) << 16);
    pk.y = f2b(fmaxf(acc[nf][2] + bva.z, 0.f)) | (f2b(fmaxf(acc[nf][3] + bva.w, 0.f)) << 16);
    *reinterpret_cast<uint2*>(&hw[col * RT + nf * 16 + kq * 4]) = pk;
  }

  // ---- phase 3: GEMM2 (B from LDS, Wb from global) ----
  f32x4 acc2[8];
#pragma unroll
  for (int nf = 0; nf < 8; ++nf) acc2[nf] = (f32x4){0.f, 0.f, 0.f, 0.f};
#pragma unroll
  for (int s = 0; s < 4; ++s) {
    const bf16x8 hb = *reinterpret_cast<const bf16x8*>(&hw[col * RT + s * 32 + kq * 8]);
#pragma unroll
    for (int nf = 0; nf < 8; ++nf) {
      const bf16x8 wb = *reinterpret_cast<const bf16x8*>(
          Wtb + ((size_t)(s * 4 + kq) * 128 + nf * 16 + col) * 8);
      acc2[nf] = __builtin_amdgcn_mfma_f32_16x16x32_bf16(wb, hb, acc2[nf], 0, 0, 0);
    }
  }
  const int m = base + col;
  if (m < NN) {
#pragma unroll
    for (int nf = 0; nf < 8; ++nf) {
      const float4 bvb = *reinterpret_cast<const float4*>(bb + nf * 16 + kq * 4);
      ushort4 p;
      p.x = (unsigned short)f2b(fmaxf(acc2[nf][0] + bvb.x, 0.f));
      p.y = (unsigned short)f2b(fmaxf(acc2[nf][1] + bvb.y, 0.f));
      p.z = (unsigned short)f2b(fmaxf(acc2[nf][2] + bvb.z, 0.f));
      p.w = (unsigned short)f2b(fmaxf(acc2[nf][3] + bvb.w, 0.f));
      *reinterpret_cast<ushort4*>(outb + (size_t)m * DF + nf * 16 + kq * 4) = p;
    }
  }
}

// ======== segment-mean pooling ========
__global__ __launch_bounds__(256) void k_pool(const unsigned short* __restrict__ h,
                                              const int* __restrict__ batch,
                                              float* __restrict__ sums,
                                              int* __restrict__ cnts)
{
  const int wv   = (blockIdx.x * 256 + threadIdx.x) >> 6;
  const int lane = threadIdx.x & 63;
  const int n0 = wv * 32;
  if (n0 >= NN) return;
  const int n1 = min(n0 + 32, NN);
  const int off = lane * 2;

  const int gfirst = batch[n0];
  const int glast  = batch[n1 - 1];
  float ax = 0.f, ay = 0.f;

  if (gfirst == glast) {
#pragma unroll 4
    for (int i = n0; i < n1; ++i) {
      const unsigned int u = *reinterpret_cast<const unsigned int*>(h + (size_t)i * DF + off);
      ax += b2f(u & 0xffff); ay += b2f(u >> 16);
    }
    atomAddF(&sums[gfirst * DF + off],     ax);
    atomAddF(&sums[gfirst * DF + off + 1], ay);
    if (lane == 0) atomicAdd(&cnts[gfirst], n1 - n0);
  } else {
    int g = gfirst, cnt = 0;
    for (int i = n0; i < n1; ++i) {
      const int gi = batch[i];
      if (gi != g) {
        atomAddF(&sums[g * DF + off],     ax);
        atomAddF(&sums[g * DF + off + 1], ay);
        if (lane == 0) atomicAdd(&cnts[g], cnt);
        ax = 0.f; ay = 0.f; cnt = 0; g = gi;
      }
      const unsigned int u = *reinterpret_cast<const unsigned int*>(h + (size_t)i * DF + off);
      ax += b2f(u & 0xffff); ay += b2f(u >> 16);
      ++cnt;
    }
    atomAddF(&sums[g * DF + off],     ax);
    atomAddF(&sums[g * DF + off + 1], ay);
    if (lane == 0) atomicAdd(&cnts[g], cnt);
  }
}

// ======== head ========
__global__ __launch_bounds__(256) void k_head(const float* __restrict__ sums,
                                              const int* __restrict__ cnts,
                                              const float* __restrict__ Wfc,
                                              const float* __restrict__ bfc,
                                              float* __restrict__ out)
{
  const int o = blockIdx.x * 256 + threadIdx.x;
  if (o >= NG * NC) return;
  const int g = o / NC, c = o % NC;
  const float inv = 1.f / fmaxf((float)cnts[g], 1.f);
  float z = bfc[c];
#pragma unroll 8
  for (int k = 0; k < DF; ++k)
    z = fmaf(sums[g * DF + k] * inv, Wfc[k * NC + c], z);
  out[o] = 1.f / (1.f + expf(-z));
}

extern "C" void kernel_launch(void* const* d_in, const int* in_sizes, int n_in,
                              void* d_out, int out_size, void* d_ws, size_t ws_size,
                              hipStream_t stream)
{
  const float* x   = (const float*)d_in[0];
  const int*   ei  = (const int*)d_in[1];
  const int* batch = (const int*)d_in[2];
  const float* W1a = (const float*)d_in[3];
  const float* b1a = (const float*)d_in[4];
  const float* W1b = (const float*)d_in[5];
  const float* b1b = (const float*)d_in[6];
  const float* W2a = (const float*)d_in[7];
  const float* b2a = (const float*)d_in[8];
  const float* W2b = (const float*)d_in[9];
  const float* b2b = (const float*)d_in[10];
  const float* Wfc = (const float*)d_in[11];
  const float* bfc = (const float*)d_in[12];
  float* out = (float*)d_out;

  const int* src = ei;           // edge_index[0]
  const int* dst = ei + NE;      // edge_index[1]

  // ws: [ushort] xb | A | H | Wt(4)  then [int/float] sums | cnts | cnt_b | rs(+pad) | es(u16) | arena
  unsigned short* xb = (unsigned short*)d_ws;
  unsigned short* A  = xb + (size_t)NN * DF;
  unsigned short* H  = A + (size_t)NN * DF;
  unsigned short* Wt = H + (size_t)NN * DF;
  float* sums  = (float*)(Wt + (size_t)4 * DF * DF);
  int*   cnts  = (int*)(sums + NG * DF);      // 64
  int*   cnt_b = cnts + 64;                   // 128
  int*   rs    = cnt_b + 128;                 // NN+1, padded to NN+4
  unsigned short* es = (unsigned short*)(rs + (NN + 4));   // NE u16
  unsigned int* arena = (unsigned int*)(es + NE);          // 98*ACAP u32

  unsigned short* Wt1a = Wt;
  unsigned short* Wt1b = Wt + DF * DF;
  unsigned short* Wt2a = Wt + 2 * DF * DF;
  unsigned short* Wt2b = Wt + 3 * DF * DF;

  const int conv_grid = (NN + 63) / 64;            // 782

  // ---- prep + CSR build ----
  hipMemsetAsync(sums, 0, (size_t)(NG * DF + 64 + 128) * sizeof(float), stream);
  k_prep_part<<<PREP_GRID + PART_GRID, 256, 0, stream>>>(
      x, xb, W1a, W1b, W2a, W2b, Wt, src, dst, cnt_b, arena);
  k_fine<<<NBK, 256, 0, stream>>>(arena, cnt_b, rs, es);

  // ---- conv1: xb -> A ----
  k_conv<<<conv_grid, 256, 0, stream>>>(xb, rs, es, Wt1a, b1a, Wt1b, b1b, A);

  // ---- conv2: A -> H ----
  k_conv<<<conv_grid, 256, 0, stream>>>(A, rs, es, Wt2a, b2a, Wt2b, b2b, H);

  // ---- pool + head ----
  k_pool<<<POOL_GRID, 256, 0, stream>>>(H, batch, sums, cnts);
  k_head<<<(NG * NC + 255) / 256, 256, 0, stream>>>(sums, cnts, Wfc, bfc, out);
}

// Round 15
// 178.187 us; speedup vs baseline: 1.1547x; 1.1547x over previous
//
#include <hip/hip_runtime.h>

#define NN 50000
#define NE 800000
#define DF 128
#define NG 64
#define NC 10
#define NBK 98            // ceil(NN/512) coarse buckets (dst>>9)
#define PART_CHUNK 4096
#define PART_GRID 196     // 196*4096 >= 800000
#define ACAP 12288        // arena capacity per bucket (avg 8163, max ~8600)
#define FINE_CAP 12288
#define RT 136            // h staging row stride (ushorts)
#define CAST_GRID 6250    // NN*DF/4/256
#define PREP_GRID (CAST_GRID + 32)
#define POOL_GRID 391     // ceil(ceil(NN/32)/4)

typedef short bf16x8 __attribute__((ext_vector_type(8)));
typedef float f32x4  __attribute__((ext_vector_type(4)));

__device__ __forceinline__ void atomAddF(float* p, float v) {
  __hip_atomic_fetch_add(p, v, __ATOMIC_RELAXED, __HIP_MEMORY_SCOPE_AGENT);
}
__device__ __forceinline__ float b2f(unsigned short u) {
  union { unsigned int i; float f; } v; v.i = (unsigned int)u << 16; return v.f;
}
__device__ __forceinline__ unsigned int f2b(float f) {
  unsigned int i = __float_as_uint(f);
  return (i + 0x7fffu + ((i >> 16) & 1u)) >> 16;
}

// ======== merged prep (cast x, weights->fragment-major) + edge partition ========
__global__ __launch_bounds__(256) void k_prep_part(const float* __restrict__ x,
                                                   unsigned short* __restrict__ xb,
                                                   const float* __restrict__ W0,
                                                   const float* __restrict__ W1,
                                                   const float* __restrict__ W2,
                                                   const float* __restrict__ W3,
                                                   unsigned short* __restrict__ Wt,
                                                   const int* __restrict__ src,
                                                   const int* __restrict__ dst,
                                                   int* __restrict__ cnt_b,
                                                   unsigned int* __restrict__ arena)
{
  __shared__ unsigned int stage[PART_CHUNK];
  __shared__ int lhist[128], lcnt[128], lcur[128], gbase[128];
  const int tid = threadIdx.x;
  const int b   = blockIdx.x;

  if (b < CAST_GRID) {
    const int i = b * 256 + tid;
    const float4 v = reinterpret_cast<const float4*>(x)[i];
    uint2 o;
    o.x = f2b(v.x) | (f2b(v.y) << 16);
    o.y = f2b(v.z) | (f2b(v.w) << 16);
    reinterpret_cast<uint2*>(xb)[i] = o;
    return;
  }
  if (b < PREP_GRID) {
    const int o = (b - CAST_GRID) * 256 + tid;
    const int mat = o >> 11;
    const float* W = (mat == 0) ? W0 : (mat == 1) ? W1 : (mat == 2) ? W2 : W3;
    const int rem = o & 2047;
    const int kb = rem >> 7, n = rem & 127;
    unsigned int u[8];
#pragma unroll
    for (int j = 0; j < 8; ++j) u[j] = f2b(W[(size_t)(kb * 8 + j) * DF + n]);
    uint4 p;
    p.x = u[0] | (u[1] << 16);
    p.y = u[2] | (u[3] << 16);
    p.z = u[4] | (u[5] << 16);
    p.w = u[6] | (u[7] << 16);
    *reinterpret_cast<uint4*>(Wt + (size_t)mat * DF * DF + (size_t)rem * 8) = p;
    return;
  }

  // ---- partition block ----
  const int vb = b - PREP_GRID;
  const int e0 = vb * PART_CHUNK;
  const int nE = min(PART_CHUNK, NE - e0);

  for (int i = tid; i < 128; i += 256) lhist[i] = 0;
  __syncthreads();
  unsigned int pk[16]; int bk[16];
#pragma unroll
  for (int i = 0; i < 16; ++i) {
    const int e = e0 + i * 256 + tid;
    if (e < NE) {
      const int d = dst[e], s = src[e];
      const int bb = d >> 9;
      bk[i] = bb;
      pk[i] = ((unsigned int)bb << 25) | ((unsigned int)(d & 511) << 16) | (unsigned int)s;
      atomicAdd(&lhist[bb], 1);
    } else bk[i] = -1;
  }
  __syncthreads();
  for (int i = tid; i < 128; i += 256) lcnt[i] = lhist[i];
  __syncthreads();
  for (int off = 1; off < 128; off <<= 1) {
    int v = 0;
    if (tid < 128 && tid >= off) v = lhist[tid - off];
    __syncthreads();
    if (tid < 128) lhist[tid] += v;
    __syncthreads();
  }
  if (tid < 128) lcur[tid] = lhist[tid] - lcnt[tid];
  __syncthreads();
#pragma unroll
  for (int i = 0; i < 16; ++i)
    if (bk[i] >= 0) {
      const int pos = atomicAdd(&lcur[bk[i]], 1);
      stage[pos] = pk[i];
    }
  __syncthreads();
  if (tid < NBK) {
    const int c = lcnt[tid];
    if (c > 0) gbase[tid] = atomicAdd(&cnt_b[tid], c);
  }
  __syncthreads();
  for (int idx = tid; idx < nE; idx += 256) {
    const unsigned int p = stage[idx];
    const int bb = (int)(p >> 25);
    const int loff = lhist[bb] - lcnt[bb];
    arena[(size_t)bb * ACAP + gbase[bb] + (idx - loff)] = p;
  }
}

// ---- per bucket: self-computed base + counting sort by (dstlocal, src>>13) ----
__global__ __launch_bounds__(256) void k_fine(const unsigned int* __restrict__ arena,
                                              const int* __restrict__ cnt_b,
                                              int* __restrict__ rs,
                                              unsigned short* __restrict__ es)
{
  __shared__ unsigned short les[FINE_CAP];   // 24 KB
  __shared__ int bins[4096];                 // 16 KB
  __shared__ int partials[256];
  __shared__ int basebuf[128];
  const int tid = threadIdx.x;
  const int b   = blockIdx.x;

  if (b == 0 && tid == 0) rs[NN] = NE;

  if (tid < 128) basebuf[tid] = (tid < NBK) ? cnt_b[tid] : 0;
  __syncthreads();
  for (int off = 1; off < 128; off <<= 1) {
    int u = 0;
    if (tid < 128 && tid >= off) u = basebuf[tid - off];
    __syncthreads();
    if (tid < 128) basebuf[tid] += u;
    __syncthreads();
  }
  const int wbase = (b == 0) ? 0 : basebuf[b - 1];
  const int cnt   = cnt_b[b];
  const int nbase = b << 9;
  const int nwin  = min(512, NN - nbase);
  const unsigned int* ap = arena + (size_t)b * ACAP;

  for (int i = tid; i < 4096; i += 256) bins[i] = 0;
  __syncthreads();
  for (int idx = tid; idx < cnt; idx += 256) {
    const unsigned int p = ap[idx];
    const int key = (int)(((p >> 16) & 511) << 3) | (int)((p & 0xffffu) >> 13);
    atomicAdd(&bins[key], 1);
  }
  __syncthreads();
  const int b16 = tid * 16;
  int sum = 0;
#pragma unroll
  for (int k = 0; k < 16; ++k) sum += bins[b16 + k];
  partials[tid] = sum;
  __syncthreads();
  for (int off = 1; off < 256; off <<= 1) {
    int u = (tid >= off) ? partials[tid - off] : 0;
    __syncthreads();
    partials[tid] += u;
    __syncthreads();
  }
  int run = partials[tid] - sum;
#pragma unroll
  for (int k = 0; k < 16; ++k) {
    const int v = bins[b16 + k];
    bins[b16 + k] = run;
    run += v;
  }
  __syncthreads();
  for (int i = tid; i < nwin; i += 256) rs[nbase + i] = wbase + bins[i << 3];
  __syncthreads();
  if (cnt <= FINE_CAP) {
    for (int idx = tid; idx < cnt; idx += 256) {
      const unsigned int p = ap[idx];
      const int key = (int)(((p >> 16) & 511) << 3) | (int)((p & 0xffffu) >> 13);
      const int pos = atomicAdd(&bins[key], 1);
      les[pos] = (unsigned short)(p & 0xffffu);
    }
    __syncthreads();
    for (int i = tid; i < cnt; i += 256) es[wbase + i] = les[i];
  } else {
    for (int idx = tid; idx < cnt; idx += 256) {
      const unsigned int p = ap[idx];
      const int key = (int)(((p >> 16) & 511) << 3) | (int)((p & 0xffffu) >> 13);
      const int pos = atomicAdd(&bins[key], 1);
      es[wbase + pos] = (unsigned short)(p & 0xffffu);
    }
  }
}

// ======== gather-aggregate: 4 quarter-wave chains, 16 rows in flight ========
// chain q (16 lanes) covers edges j+4p+q; uint4/lane = full 256B row per chain.
__global__ __launch_bounds__(256) void k_gather(const unsigned short* __restrict__ feat,
                                                unsigned short* __restrict__ outp,
                                                const int* __restrict__ rs,
                                                const unsigned short* __restrict__ es)
{
  const int wid  = (blockIdx.x * 256 + threadIdx.x) >> 6;
  const int lane = threadIdx.x & 63;
  if (wid >= NN) return;
  const int q   = lane >> 4;        // chain 0..3
  const int l16 = lane & 15;
  const int off = l16 * 8;          // 8 feats per lane
  const int beg = rs[wid];
  const int end = rs[wid + 1];

  float a0 = 0.f, a1 = 0.f, a2 = 0.f, a3 = 0.f;
  float a4 = 0.f, a5 = 0.f, a6 = 0.f, a7 = 0.f;
  if (q == 0) {
    const uint4 u = *reinterpret_cast<const uint4*>(feat + (size_t)wid * DF + off);
    a0 = b2f(u.x & 0xffff); a1 = b2f(u.x >> 16);
    a2 = b2f(u.y & 0xffff); a3 = b2f(u.y >> 16);
    a4 = b2f(u.z & 0xffff); a5 = b2f(u.z >> 16);
    a6 = b2f(u.w & 0xffff); a7 = b2f(u.w >> 16);
  }

  int j = beg;
  for (; j + 15 < end; j += 16) {
    const int i0 = es[j + q];
    const int i1 = es[j + 4 + q];
    const int i2 = es[j + 8 + q];
    const int i3 = es[j + 12 + q];
    const uint4 u0 = *reinterpret_cast<const uint4*>(feat + (size_t)i0 * DF + off);
    const uint4 u1 = *reinterpret_cast<const uint4*>(feat + (size_t)i1 * DF + off);
    const uint4 u2 = *reinterpret_cast<const uint4*>(feat + (size_t)i2 * DF + off);
    const uint4 u3 = *reinterpret_cast<const uint4*>(feat + (size_t)i3 * DF + off);
    a0 += b2f(u0.x & 0xffff) + b2f(u1.x & 0xffff) + b2f(u2.x & 0xffff) + b2f(u3.x & 0xffff);
    a1 += b2f(u0.x >> 16)    + b2f(u1.x >> 16)    + b2f(u2.x >> 16)    + b2f(u3.x >> 16);
    a2 += b2f(u0.y & 0xffff) + b2f(u1.y & 0xffff) + b2f(u2.y & 0xffff) + b2f(u3.y & 0xffff);
    a3 += b2f(u0.y >> 16)    + b2f(u1.y >> 16)    + b2f(u2.y >> 16)    + b2f(u3.y >> 16);
    a4 += b2f(u0.z & 0xffff) + b2f(u1.z & 0xffff) + b2f(u2.z & 0xffff) + b2f(u3.z & 0xffff);
    a5 += b2f(u0.z >> 16)    + b2f(u1.z >> 16)    + b2f(u2.z >> 16)    + b2f(u3.z >> 16);
    a6 += b2f(u0.w & 0xffff) + b2f(u1.w & 0xffff) + b2f(u2.w & 0xffff) + b2f(u3.w & 0xffff);
    a7 += b2f(u0.w >> 16)    + b2f(u1.w >> 16)    + b2f(u2.w >> 16)    + b2f(u3.w >> 16);
  }
  for (; j + 3 < end; j += 4) {
    const int i = es[j + q];
    const uint4 u = *reinterpret_cast<const uint4*>(feat + (size_t)i * DF + off);
    a0 += b2f(u.x & 0xffff); a1 += b2f(u.x >> 16);
    a2 += b2f(u.y & 0xffff); a3 += b2f(u.y >> 16);
    a4 += b2f(u.z & 0xffff); a5 += b2f(u.z >> 16);
    a6 += b2f(u.w & 0xffff); a7 += b2f(u.w >> 16);
  }
  if (j + q < end) {
    const int i = es[j + q];
    const uint4 u = *reinterpret_cast<const uint4*>(feat + (size_t)i * DF + off);
    a0 += b2f(u.x & 0xffff); a1 += b2f(u.x >> 16);
    a2 += b2f(u.y & 0xffff); a3 += b2f(u.y >> 16);
    a4 += b2f(u.z & 0xffff); a5 += b2f(u.z >> 16);
    a6 += b2f(u.w & 0xffff); a7 += b2f(u.w >> 16);
  }

  // combine the four chains
  a0 += __shfl_xor(a0, 16); a1 += __shfl_xor(a1, 16);
  a2 += __shfl_xor(a2, 16); a3 += __shfl_xor(a3, 16);
  a4 += __shfl_xor(a4, 16); a5 += __shfl_xor(a5, 16);
  a6 += __shfl_xor(a6, 16); a7 += __shfl_xor(a7, 16);
  a0 += __shfl_xor(a0, 32); a1 += __shfl_xor(a1, 32);
  a2 += __shfl_xor(a2, 32); a3 += __shfl_xor(a3, 32);
  a4 += __shfl_xor(a4, 32); a5 += __shfl_xor(a5, 32);
  a6 += __shfl_xor(a6, 32); a7 += __shfl_xor(a7, 32);

  if (q == 0) {
    uint4 o;
    o.x = f2b(a0) | (f2b(a1) << 16);
    o.y = f2b(a2) | (f2b(a3) << 16);
    o.z = f2b(a4) | (f2b(a5) << 16);
    o.w = f2b(a6) | (f2b(a7) << 16);
    *reinterpret_cast<uint4*>(outp + (size_t)wid * DF + off) = o;
  }
}

// ======== fused double GEMM: out = relu(relu(A@Wa+ba)@Wb+bb), bf16 MFMA ========
__global__ __launch_bounds__(256, 4) void k_gemm2(const unsigned short* __restrict__ Ab,
                                                  const unsigned short* __restrict__ Wta,
                                                  const float* __restrict__ ba,
                                                  const unsigned short* __restrict__ Wtb,
                                                  const float* __restrict__ bb,
                                                  unsigned short* __restrict__ outb, int M)
{
  __shared__ unsigned short hL[4][16 * RT];     // 17.4 KB
  const int tid  = threadIdx.x;
  const int lane = tid & 63;
  const int w    = tid >> 6;
  const int col  = lane & 15;
  const int kq   = lane >> 4;

  const int m   = blockIdx.x * 64 + w * 16 + col;
  const int mld = (m < M) ? m : (M - 1);

  bf16x8 bc[4];
#pragma unroll
  for (int s = 0; s < 4; ++s)
    bc[s] = *reinterpret_cast<const bf16x8*>(Ab + (size_t)mld * DF + s * 32 + kq * 8);

  f32x4 acc[8];
#pragma unroll
  for (int nf = 0; nf < 8; ++nf) acc[nf] = (f32x4){0.f, 0.f, 0.f, 0.f};
#pragma unroll
  for (int s = 0; s < 4; ++s) {
#pragma unroll
    for (int nf = 0; nf < 8; ++nf) {
      const bf16x8 wa = *reinterpret_cast<const bf16x8*>(
          Wta + ((size_t)(s * 4 + kq) * 128 + nf * 16 + col) * 8);
      acc[nf] = __builtin_amdgcn_mfma_f32_16x16x32_bf16(wa, bc[s], acc[nf], 0, 0, 0);
    }
  }

  unsigned short* hw = &hL[w][0];
#pragma unroll
  for (int nf = 0; nf < 8; ++nf) {
    const float4 bva = *reinterpret_cast<const float4*>(ba + nf * 16 + kq * 4);
    uint2 pk;
    pk.x = f2b(fmaxf(acc[nf][0] + bva.x, 0.f)) | (f2b(fmaxf(acc[nf][1] + bva.y, 0.f)) << 16);
    pk.y = f2b(fmaxf(acc[nf][2] + bva.z, 0.f)) | (f2b(fmaxf(acc[nf][3] + bva.w, 0.f)) << 16);
    *reinterpret_cast<uint2*>(&hw[col * RT + nf * 16 + kq * 4]) = pk;
  }
  // ds_write -> ds_read dependency tracked by compiler (wave-private buffer)

  f32x4 acc2[8];
#pragma unroll
  for (int nf = 0; nf < 8; ++nf) acc2[nf] = (f32x4){0.f, 0.f, 0.f, 0.f};
#pragma unroll
  for (int s = 0; s < 4; ++s) {
    const bf16x8 hb = *reinterpret_cast<const bf16x8*>(&hw[col * RT + s * 32 + kq * 8]);
#pragma unroll
    for (int nf = 0; nf < 8; ++nf) {
      const bf16x8 wb = *reinterpret_cast<const bf16x8*>(
          Wtb + ((size_t)(s * 4 + kq) * 128 + nf * 16 + col) * 8);
      acc2[nf] = __builtin_amdgcn_mfma_f32_16x16x32_bf16(wb, hb, acc2[nf], 0, 0, 0);
    }
  }
  if (m < M) {
#pragma unroll
    for (int nf = 0; nf < 8; ++nf) {
      const float4 bvb = *reinterpret_cast<const float4*>(bb + nf * 16 + kq * 4);
      ushort4 p;
      p.x = (unsigned short)f2b(fmaxf(acc2[nf][0] + bvb.x, 0.f));
      p.y = (unsigned short)f2b(fmaxf(acc2[nf][1] + bvb.y, 0.f));
      p.z = (unsigned short)f2b(fmaxf(acc2[nf][2] + bvb.z, 0.f));
      p.w = (unsigned short)f2b(fmaxf(acc2[nf][3] + bvb.w, 0.f));
      *reinterpret_cast<ushort4*>(outb + (size_t)m * DF + nf * 16 + kq * 4) = p;
    }
  }
}

// ======== segment-mean pooling ========
__global__ __launch_bounds__(256) void k_pool(const unsigned short* __restrict__ h,
                                              const int* __restrict__ batch,
                                              float* __restrict__ sums,
                                              int* __restrict__ cnts)
{
  const int wv   = (blockIdx.x * 256 + threadIdx.x) >> 6;
  const int lane = threadIdx.x & 63;
  const int n0 = wv * 32;
  if (n0 >= NN) return;
  const int n1 = min(n0 + 32, NN);
  const int off = lane * 2;

  const int gfirst = batch[n0];
  const int glast  = batch[n1 - 1];
  float ax = 0.f, ay = 0.f;

  if (gfirst == glast) {
#pragma unroll 4
    for (int i = n0; i < n1; ++i) {
      const unsigned int u = *reinterpret_cast<const unsigned int*>(h + (size_t)i * DF + off);
      ax += b2f(u & 0xffff); ay += b2f(u >> 16);
    }
    atomAddF(&sums[gfirst * DF + off],     ax);
    atomAddF(&sums[gfirst * DF + off + 1], ay);
    if (lane == 0) atomicAdd(&cnts[gfirst], n1 - n0);
  } else {
    int g = gfirst, cnt = 0;
    for (int i = n0; i < n1; ++i) {
      const int gi = batch[i];
      if (gi != g) {
        atomAddF(&sums[g * DF + off],     ax);
        atomAddF(&sums[g * DF + off + 1], ay);
        if (lane == 0) atomicAdd(&cnts[g], cnt);
        ax = 0.f; ay = 0.f; cnt = 0; g = gi;
      }
      const unsigned int u = *reinterpret_cast<const unsigned int*>(h + (size_t)i * DF + off);
      ax += b2f(u & 0xffff); ay += b2f(u >> 16);
      ++cnt;
    }
    atomAddF(&sums[g * DF + off],     ax);
    atomAddF(&sums[g * DF + off + 1], ay);
    if (lane == 0) atomicAdd(&cnts[g], cnt);
  }
}

// ======== head ========
__global__ __launch_bounds__(256) void k_head(const float* __restrict__ sums,
                                              const int* __restrict__ cnts,
                                              const float* __restrict__ Wfc,
                                              const float* __restrict__ bfc,
                                              float* __restrict__ out)
{
  const int o = blockIdx.x * 256 + threadIdx.x;
  if (o >= NG * NC) return;
  const int g = o / NC, c = o % NC;
  const float inv = 1.f / fmaxf((float)cnts[g], 1.f);
  float z = bfc[c];
#pragma unroll 8
  for (int k = 0; k < DF; ++k)
    z = fmaf(sums[g * DF + k] * inv, Wfc[k * NC + c], z);
  out[o] = 1.f / (1.f + expf(-z));
}

extern "C" void kernel_launch(void* const* d_in, const int* in_sizes, int n_in,
                              void* d_out, int out_size, void* d_ws, size_t ws_size,
                              hipStream_t stream)
{
  const float* x   = (const float*)d_in[0];
  const int*   ei  = (const int*)d_in[1];
  const int* batch = (const int*)d_in[2];
  const float* W1a = (const float*)d_in[3];
  const float* b1a = (const float*)d_in[4];
  const float* W1b = (const float*)d_in[5];
  const float* b1b = (const float*)d_in[6];
  const float* W2a = (const float*)d_in[7];
  const float* b2a = (const float*)d_in[8];
  const float* W2b = (const float*)d_in[9];
  const float* b2b = (const float*)d_in[10];
  const float* Wfc = (const float*)d_in[11];
  const float* bfc = (const float*)d_in[12];
  float* out = (float*)d_out;

  const int* src = ei;           // edge_index[0]
  const int* dst = ei + NE;      // edge_index[1]

  // ws: [ushort] xb | A | H | Wt(4)  then [int/float] sums | cnts | cnt_b | rs(+pad) | es(u16) | arena
  unsigned short* xb = (unsigned short*)d_ws;
  unsigned short* A  = xb + (size_t)NN * DF;
  unsigned short* H  = A + (size_t)NN * DF;
  unsigned short* Wt = H + (size_t)NN * DF;
  float* sums  = (float*)(Wt + (size_t)4 * DF * DF);
  int*   cnts  = (int*)(sums + NG * DF);      // 64
  int*   cnt_b = cnts + 64;                   // 128
  int*   rs    = cnt_b + 128;                 // NN+1, padded to NN+4
  unsigned short* es = (unsigned short*)(rs + (NN + 4));   // NE u16
  unsigned int* arena = (unsigned int*)(es + NE);          // 98*ACAP u32

  unsigned short* Wt1a = Wt;
  unsigned short* Wt1b = Wt + DF * DF;
  unsigned short* Wt2a = Wt + 2 * DF * DF;
  unsigned short* Wt2b = Wt + 3 * DF * DF;

  const int gemm_grid   = (NN + 63) / 64;            // 782
  const int gather_grid = (NN * 64 + 255) / 256;     // 12500

  // ---- prep + CSR build ----
  hipMemsetAsync(sums, 0, (size_t)(NG * DF + 64 + 128) * sizeof(float), stream);
  k_prep_part<<<PREP_GRID + PART_GRID, 256, 0, stream>>>(
      x, xb, W1a, W1b, W2a, W2b, Wt, src, dst, cnt_b, arena);
  k_fine<<<NBK, 256, 0, stream>>>(arena, cnt_b, rs, es);

  // ---- conv1 ----
  k_gather<<<gather_grid, 256, 0, stream>>>(xb, A, rs, es);
  k_gemm2<<<gemm_grid, 256, 0, stream>>>(A, Wt1a, b1a, Wt1b, b1b, A, NN);

  // ---- conv2 ----
  k_gather<<<gather_grid, 256, 0, stream>>>(A, H, rs, es);
  k_gemm2<<<gemm_grid, 256, 0, stream>>>(H, Wt2a, b2a, Wt2b, b2b, H, NN);

  // ---- pool + head ----
  k_pool<<<POOL_GRID, 256, 0, stream>>>(H, batch, sums, cnts);
  k_head<<<(NG * NC + 255) / 256, 256, 0, stream>>>(sums, cnts, Wfc, bfc, out);
}

// Round 16
// 172.370 us; speedup vs baseline: 1.1937x; 1.0337x over previous
//
#include <hip/hip_runtime.h>

#define NN 50000
#define NE 800000
#define DF 128
#define NG 64
#define NC 10
#define NBK 391           // ceil(NN/128) buckets (dst>>7)
#define PART_CHUNK 2048
#define PART_GRID 391     // 391*2048 >= 800000
#define ACAP 3072         // arena capacity per bucket (avg 2046, sigma~45)
#define FINE_CAP 3072
#define RT 136            // h staging row stride (ushorts)
#define CAST_GRID 6250    // NN*DF/4/256
#define PREP_GRID (CAST_GRID + 32)
#define POOL_GRID 391     // ceil(ceil(NN/32)/4)

typedef short bf16x8 __attribute__((ext_vector_type(8)));
typedef float f32x4  __attribute__((ext_vector_type(4)));

__device__ __forceinline__ void atomAddF(float* p, float v) {
  __hip_atomic_fetch_add(p, v, __ATOMIC_RELAXED, __HIP_MEMORY_SCOPE_AGENT);
}
__device__ __forceinline__ float b2f(unsigned short u) {
  union { unsigned int i; float f; } v; v.i = (unsigned int)u << 16; return v.f;
}
__device__ __forceinline__ unsigned int f2b(float f) {
  unsigned int i = __float_as_uint(f);
  return (i + 0x7fffu + ((i >> 16) & 1u)) >> 16;
}

// ======== merged prep (cast x, weights->fragment-major) + edge partition ========
// pack = (bucket<<23) | (dstlocal<<16) | src   (9+7+16 bits)
__global__ __launch_bounds__(256) void k_prep_part(const float* __restrict__ x,
                                                   unsigned short* __restrict__ xb,
                                                   const float* __restrict__ W0,
                                                   const float* __restrict__ W1,
                                                   const float* __restrict__ W2,
                                                   const float* __restrict__ W3,
                                                   unsigned short* __restrict__ Wt,
                                                   const int* __restrict__ src,
                                                   const int* __restrict__ dst,
                                                   int* __restrict__ cnt_b,
                                                   unsigned int* __restrict__ arena)
{
  __shared__ unsigned int stage[PART_CHUNK];            // 8 KB
  __shared__ int lhist[512], lcnt[512], lcur[512], gbase[512];  // 8 KB
  __shared__ int pscan[256];
  const int tid = threadIdx.x;
  const int b   = blockIdx.x;

  if (b < CAST_GRID) {
    const int i = b * 256 + tid;
    const float4 v = reinterpret_cast<const float4*>(x)[i];
    uint2 o;
    o.x = f2b(v.x) | (f2b(v.y) << 16);
    o.y = f2b(v.z) | (f2b(v.w) << 16);
    reinterpret_cast<uint2*>(xb)[i] = o;
    return;
  }
  if (b < PREP_GRID) {
    const int o = (b - CAST_GRID) * 256 + tid;
    const int mat = o >> 11;
    const float* W = (mat == 0) ? W0 : (mat == 1) ? W1 : (mat == 2) ? W2 : W3;
    const int rem = o & 2047;
    const int kb = rem >> 7, n = rem & 127;
    unsigned int u[8];
#pragma unroll
    for (int j = 0; j < 8; ++j) u[j] = f2b(W[(size_t)(kb * 8 + j) * DF + n]);
    uint4 p;
    p.x = u[0] | (u[1] << 16);
    p.y = u[2] | (u[3] << 16);
    p.z = u[4] | (u[5] << 16);
    p.w = u[6] | (u[7] << 16);
    *reinterpret_cast<uint4*>(Wt + (size_t)mat * DF * DF + (size_t)rem * 8) = p;
    return;
  }

  // ---- partition block ----
  const int vb = b - PREP_GRID;
  const int e0 = vb * PART_CHUNK;
  const int nE = min(PART_CHUNK, NE - e0);

  for (int i = tid; i < 512; i += 256) lhist[i] = 0;
  __syncthreads();
  unsigned int pk[8]; int bk[8];
#pragma unroll
  for (int i = 0; i < 8; ++i) {
    const int e = e0 + i * 256 + tid;
    if (e < NE) {
      const int d = dst[e], s = src[e];
      const int bb = d >> 7;
      bk[i] = bb;
      pk[i] = ((unsigned int)bb << 23) | ((unsigned int)(d & 127) << 16) | (unsigned int)s;
      atomicAdd(&lhist[bb], 1);
    } else bk[i] = -1;
  }
  __syncthreads();
  for (int i = tid; i < 512; i += 256) lcnt[i] = lhist[i];
  __syncthreads();
  // exclusive scan over 512 entries via pair-sum + 256-scan
  const int s0 = lhist[2 * tid];
  const int s1 = lhist[2 * tid + 1];
  pscan[tid] = s0 + s1;
  __syncthreads();
  for (int off = 1; off < 256; off <<= 1) {
    int u = (tid >= off) ? pscan[tid - off] : 0;
    __syncthreads();
    pscan[tid] += u;
    __syncthreads();
  }
  const int ep = pscan[tid] - s0 - s1;
  __syncthreads();
  lhist[2 * tid]     = ep;        // exclusive offsets
  lhist[2 * tid + 1] = ep + s0;
  lcur[2 * tid]      = ep;        // running cursors
  lcur[2 * tid + 1]  = ep + s0;
  __syncthreads();
#pragma unroll
  for (int i = 0; i < 8; ++i)
    if (bk[i] >= 0) {
      const int pos = atomicAdd(&lcur[bk[i]], 1);
      stage[pos] = pk[i];
    }
  __syncthreads();
  for (int i = tid; i < 512; i += 256) {
    if (i < NBK) {
      const int c = lcnt[i];
      if (c > 0) gbase[i] = atomicAdd(&cnt_b[i], c);
    }
  }
  __syncthreads();
  for (int idx = tid; idx < nE; idx += 256) {
    const unsigned int p = stage[idx];
    const int bb = (int)(p >> 23);
    arena[(size_t)bb * ACAP + gbase[bb] + (idx - lhist[bb])] = p;
  }
}

// ---- per bucket (128 nodes): self-computed base + counting sort by (dstlocal, src>>13) ----
__global__ __launch_bounds__(256) void k_fine(const unsigned int* __restrict__ arena,
                                              const int* __restrict__ cnt_b,
                                              int* __restrict__ rs,
                                              unsigned short* __restrict__ es)
{
  __shared__ unsigned short les[FINE_CAP];   // 6 KB
  __shared__ int bins[1024];                 // 4 KB
  __shared__ int partials[256];
  __shared__ int basebuf[512];
  __shared__ int bpair[256];
  const int tid = threadIdx.x;
  const int b   = blockIdx.x;

  if (b == 0 && tid == 0) rs[NN] = NE;

  // exclusive scan of cnt_b[0..NBK) (512-padded) to get this bucket's write base
  for (int i = tid; i < 512; i += 256) basebuf[i] = (i < NBK) ? cnt_b[i] : 0;
  __syncthreads();
  const int t0 = basebuf[2 * tid];
  const int t1 = basebuf[2 * tid + 1];
  bpair[tid] = t0 + t1;
  __syncthreads();
  for (int off = 1; off < 256; off <<= 1) {
    int u = (tid >= off) ? bpair[tid - off] : 0;
    __syncthreads();
    bpair[tid] += u;
    __syncthreads();
  }
  const int eb = bpair[tid] - t0 - t1;
  __syncthreads();
  basebuf[2 * tid]     = eb;
  basebuf[2 * tid + 1] = eb + t0;
  __syncthreads();
  const int wbase = basebuf[b];
  const int cnt   = cnt_b[b];
  const int nbase = b << 7;
  const int nwin  = min(128, NN - nbase);
  const unsigned int* ap = arena + (size_t)b * ACAP;

  for (int i = tid; i < 1024; i += 256) bins[i] = 0;
  __syncthreads();
  for (int idx = tid; idx < cnt; idx += 256) {
    const unsigned int p = ap[idx];
    const int key = (int)(((p >> 16) & 127) << 3) | (int)((p & 0xffffu) >> 13);
    atomicAdd(&bins[key], 1);
  }
  __syncthreads();
  const int b4 = tid * 4;
  int sum = bins[b4] + bins[b4 + 1] + bins[b4 + 2] + bins[b4 + 3];
  partials[tid] = sum;
  __syncthreads();
  for (int off = 1; off < 256; off <<= 1) {
    int u = (tid >= off) ? partials[tid - off] : 0;
    __syncthreads();
    partials[tid] += u;
    __syncthreads();
  }
  int run = partials[tid] - sum;
#pragma unroll
  for (int k = 0; k < 4; ++k) {
    const int v = bins[b4 + k];
    bins[b4 + k] = run;
    run += v;
  }
  __syncthreads();
  for (int i = tid; i < nwin; i += 256) rs[nbase + i] = wbase + bins[i << 3];
  __syncthreads();
  if (cnt <= FINE_CAP) {
    for (int idx = tid; idx < cnt; idx += 256) {
      const unsigned int p = ap[idx];
      const int key = (int)(((p >> 16) & 127) << 3) | (int)((p & 0xffffu) >> 13);
      const int pos = atomicAdd(&bins[key], 1);
      les[pos] = (unsigned short)(p & 0xffffu);
    }
    __syncthreads();
    for (int i = tid; i < cnt; i += 256) es[wbase + i] = les[i];
  } else {   // statistically unreachable fallback
    for (int idx = tid; idx < cnt; idx += 256) {
      const unsigned int p = ap[idx];
      const int key = (int)(((p >> 16) & 127) << 3) | (int)((p & 0xffffu) >> 13);
      const int pos = atomicAdd(&bins[key], 1);
      es[wbase + pos] = (unsigned short)(p & 0xffffu);
    }
  }
}

// ======== gather-aggregate: 4 quarter-wave chains, 16 rows in flight ========
__global__ __launch_bounds__(256) void k_gather(const unsigned short* __restrict__ feat,
                                                unsigned short* __restrict__ outp,
                                                const int* __restrict__ rs,
                                                const unsigned short* __restrict__ es)
{
  const int wid  = (blockIdx.x * 256 + threadIdx.x) >> 6;
  const int lane = threadIdx.x & 63;
  if (wid >= NN) return;
  const int q   = lane >> 4;        // chain 0..3
  const int l16 = lane & 15;
  const int off = l16 * 8;          // 8 feats per lane
  const int beg = rs[wid];
  const int end = rs[wid + 1];

  float a0 = 0.f, a1 = 0.f, a2 = 0.f, a3 = 0.f;
  float a4 = 0.f, a5 = 0.f, a6 = 0.f, a7 = 0.f;
  if (q == 0) {
    const uint4 u = *reinterpret_cast<const uint4*>(feat + (size_t)wid * DF + off);
    a0 = b2f(u.x & 0xffff); a1 = b2f(u.x >> 16);
    a2 = b2f(u.y & 0xffff); a3 = b2f(u.y >> 16);
    a4 = b2f(u.z & 0xffff); a5 = b2f(u.z >> 16);
    a6 = b2f(u.w & 0xffff); a7 = b2f(u.w >> 16);
  }

  int j = beg;
  for (; j + 15 < end; j += 16) {
    const int i0 = es[j + q];
    const int i1 = es[j + 4 + q];
    const int i2 = es[j + 8 + q];
    const int i3 = es[j + 12 + q];
    const uint4 u0 = *reinterpret_cast<const uint4*>(feat + (size_t)i0 * DF + off);
    const uint4 u1 = *reinterpret_cast<const uint4*>(feat + (size_t)i1 * DF + off);
    const uint4 u2 = *reinterpret_cast<const uint4*>(feat + (size_t)i2 * DF + off);
    const uint4 u3 = *reinterpret_cast<const uint4*>(feat + (size_t)i3 * DF + off);
    a0 += b2f(u0.x & 0xffff) + b2f(u1.x & 0xffff) + b2f(u2.x & 0xffff) + b2f(u3.x & 0xffff);
    a1 += b2f(u0.x >> 16)    + b2f(u1.x >> 16)    + b2f(u2.x >> 16)    + b2f(u3.x >> 16);
    a2 += b2f(u0.y & 0xffff) + b2f(u1.y & 0xffff) + b2f(u2.y & 0xffff) + b2f(u3.y & 0xffff);
    a3 += b2f(u0.y >> 16)    + b2f(u1.y >> 16)    + b2f(u2.y >> 16)    + b2f(u3.y >> 16);
    a4 += b2f(u0.z & 0xffff) + b2f(u1.z & 0xffff) + b2f(u2.z & 0xffff) + b2f(u3.z & 0xffff);
    a5 += b2f(u0.z >> 16)    + b2f(u1.z >> 16)    + b2f(u2.z >> 16)    + b2f(u3.z >> 16);
    a6 += b2f(u0.w & 0xffff) + b2f(u1.w & 0xffff) + b2f(u2.w & 0xffff) + b2f(u3.w & 0xffff);
    a7 += b2f(u0.w >> 16)    + b2f(u1.w >> 16)    + b2f(u2.w >> 16)    + b2f(u3.w >> 16);
  }
  for (; j + 3 < end; j += 4) {
    const int i = es[j + q];
    const uint4 u = *reinterpret_cast<const uint4*>(feat + (size_t)i * DF + off);
    a0 += b2f(u.x & 0xffff); a1 += b2f(u.x >> 16);
    a2 += b2f(u.y & 0xffff); a3 += b2f(u.y >> 16);
    a4 += b2f(u.z & 0xffff); a5 += b2f(u.z >> 16);
    a6 += b2f(u.w & 0xffff); a7 += b2f(u.w >> 16);
  }
  if (j + q < end) {
    const int i = es[j + q];
    const uint4 u = *reinterpret_cast<const uint4*>(feat + (size_t)i * DF + off);
    a0 += b2f(u.x & 0xffff); a1 += b2f(u.x >> 16);
    a2 += b2f(u.y & 0xffff); a3 += b2f(u.y >> 16);
    a4 += b2f(u.z & 0xffff); a5 += b2f(u.z >> 16);
    a6 += b2f(u.w & 0xffff); a7 += b2f(u.w >> 16);
  }

  a0 += __shfl_xor(a0, 16); a1 += __shfl_xor(a1, 16);
  a2 += __shfl_xor(a2, 16); a3 += __shfl_xor(a3, 16);
  a4 += __shfl_xor(a4, 16); a5 += __shfl_xor(a5, 16);
  a6 += __shfl_xor(a6, 16); a7 += __shfl_xor(a7, 16);
  a0 += __shfl_xor(a0, 32); a1 += __shfl_xor(a1, 32);
  a2 += __shfl_xor(a2, 32); a3 += __shfl_xor(a3, 32);
  a4 += __shfl_xor(a4, 32); a5 += __shfl_xor(a5, 32);
  a6 += __shfl_xor(a6, 32); a7 += __shfl_xor(a7, 32);

  if (q == 0) {
    uint4 o;
    o.x = f2b(a0) | (f2b(a1) << 16);
    o.y = f2b(a2) | (f2b(a3) << 16);
    o.z = f2b(a4) | (f2b(a5) << 16);
    o.w = f2b(a6) | (f2b(a7) << 16);
    *reinterpret_cast<uint4*>(outp + (size_t)wid * DF + off) = o;
  }
}

// ======== fused double GEMM: out = relu(relu(A@Wa+ba)@Wb+bb), bf16 MFMA ========
__global__ __launch_bounds__(256, 4) void k_gemm2(const unsigned short* __restrict__ Ab,
                                                  const unsigned short* __restrict__ Wta,
                                                  const float* __restrict__ ba,
                                                  const unsigned short* __restrict__ Wtb,
                                                  const float* __restrict__ bb,
                                                  unsigned short* __restrict__ outb, int M)
{
  __shared__ unsigned short hL[4][16 * RT];     // 17.4 KB
  const int tid  = threadIdx.x;
  const int lane = tid & 63;
  const int w    = tid >> 6;
  const int col  = lane & 15;
  const int kq   = lane >> 4;

  const int m   = blockIdx.x * 64 + w * 16 + col;
  const int mld = (m < M) ? m : (M - 1);

  bf16x8 bc[4];
#pragma unroll
  for (int s = 0; s < 4; ++s)
    bc[s] = *reinterpret_cast<const bf16x8*>(Ab + (size_t)mld * DF + s * 32 + kq * 8);

  f32x4 acc[8];
#pragma unroll
  for (int nf = 0; nf < 8; ++nf) acc[nf] = (f32x4){0.f, 0.f, 0.f, 0.f};
#pragma unroll
  for (int s = 0; s < 4; ++s) {
#pragma unroll
    for (int nf = 0; nf < 8; ++nf) {
      const bf16x8 wa = *reinterpret_cast<const bf16x8*>(
          Wta + ((size_t)(s * 4 + kq) * 128 + nf * 16 + col) * 8);
      acc[nf] = __builtin_amdgcn_mfma_f32_16x16x32_bf16(wa, bc[s], acc[nf], 0, 0, 0);
    }
  }

  unsigned short* hw = &hL[w][0];
#pragma unroll
  for (int nf = 0; nf < 8; ++nf) {
    const float4 bva = *reinterpret_cast<const float4*>(ba + nf * 16 + kq * 4);
    uint2 pk;
    pk.x = f2b(fmaxf(acc[nf][0] + bva.x, 0.f)) | (f2b(fmaxf(acc[nf][1] + bva.y, 0.f)) << 16);
    pk.y = f2b(fmaxf(acc[nf][2] + bva.z, 0.f)) | (f2b(fmaxf(acc[nf][3] + bva.w, 0.f)) << 16);
    *reinterpret_cast<uint2*>(&hw[col * RT + nf * 16 + kq * 4]) = pk;
  }
  // ds_write -> ds_read dependency tracked by compiler (wave-private buffer)

  f32x4 acc2[8];
#pragma unroll
  for (int nf = 0; nf < 8; ++nf) acc2[nf] = (f32x4){0.f, 0.f, 0.f, 0.f};
#pragma unroll
  for (int s = 0; s < 4; ++s) {
    const bf16x8 hb = *reinterpret_cast<const bf16x8*>(&hw[col * RT + s * 32 + kq * 8]);
#pragma unroll
    for (int nf = 0; nf < 8; ++nf) {
      const bf16x8 wb = *reinterpret_cast<const bf16x8*>(
          Wtb + ((size_t)(s * 4 + kq) * 128 + nf * 16 + col) * 8);
      acc2[nf] = __builtin_amdgcn_mfma_f32_16x16x32_bf16(wb, hb, acc2[nf], 0, 0, 0);
    }
  }
  if (m < M) {
#pragma unroll
    for (int nf = 0; nf < 8; ++nf) {
      const float4 bvb = *reinterpret_cast<const float4*>(bb + nf * 16 + kq * 4);
      ushort4 p;
      p.x = (unsigned short)f2b(fmaxf(acc2[nf][0] + bvb.x, 0.f));
      p.y = (unsigned short)f2b(fmaxf(acc2[nf][1] + bvb.y, 0.f));
      p.z = (unsigned short)f2b(fmaxf(acc2[nf][2] + bvb.z, 0.f));
      p.w = (unsigned short)f2b(fmaxf(acc2[nf][3] + bvb.w, 0.f));
      *reinterpret_cast<ushort4*>(outb + (size_t)m * DF + nf * 16 + kq * 4) = p;
    }
  }
}

// ======== segment-mean pooling ========
__global__ __launch_bounds__(256) void k_pool(const unsigned short* __restrict__ h,
                                              const int* __restrict__ batch,
                                              float* __restrict__ sums,
                                              int* __restrict__ cnts)
{
  const int wv   = (blockIdx.x * 256 + threadIdx.x) >> 6;
  const int lane = threadIdx.x & 63;
  const int n0 = wv * 32;
  if (n0 >= NN) return;
  const int n1 = min(n0 + 32, NN);
  const int off = lane * 2;

  const int gfirst = batch[n0];
  const int glast  = batch[n1 - 1];
  float ax = 0.f, ay = 0.f;

  if (gfirst == glast) {
#pragma unroll 4
    for (int i = n0; i < n1; ++i) {
      const unsigned int u = *reinterpret_cast<const unsigned int*>(h + (size_t)i * DF + off);
      ax += b2f(u & 0xffff); ay += b2f(u >> 16);
    }
    atomAddF(&sums[gfirst * DF + off],     ax);
    atomAddF(&sums[gfirst * DF + off + 1], ay);
    if (lane == 0) atomicAdd(&cnts[gfirst], n1 - n0);
  } else {
    int g = gfirst, cnt = 0;
    for (int i = n0; i < n1; ++i) {
      const int gi = batch[i];
      if (gi != g) {
        atomAddF(&sums[g * DF + off],     ax);
        atomAddF(&sums[g * DF + off + 1], ay);
        if (lane == 0) atomicAdd(&cnts[g], cnt);
        ax = 0.f; ay = 0.f; cnt = 0; g = gi;
      }
      const unsigned int u = *reinterpret_cast<const unsigned int*>(h + (size_t)i * DF + off);
      ax += b2f(u & 0xffff); ay += b2f(u >> 16);
      ++cnt;
    }
    atomAddF(&sums[g * DF + off],     ax);
    atomAddF(&sums[g * DF + off + 1], ay);
    if (lane == 0) atomicAdd(&cnts[g], cnt);
  }
}

// ======== head ========
__global__ __launch_bounds__(256) void k_head(const float* __restrict__ sums,
                                              const int* __restrict__ cnts,
                                              const float* __restrict__ Wfc,
                                              const float* __restrict__ bfc,
                                              float* __restrict__ out)
{
  const int o = blockIdx.x * 256 + threadIdx.x;
  if (o >= NG * NC) return;
  const int g = o / NC, c = o % NC;
  const float inv = 1.f / fmaxf((float)cnts[g], 1.f);
  float z = bfc[c];
#pragma unroll 8
  for (int k = 0; k < DF; ++k)
    z = fmaf(sums[g * DF + k] * inv, Wfc[k * NC + c], z);
  out[o] = 1.f / (1.f + expf(-z));
}

extern "C" void kernel_launch(void* const* d_in, const int* in_sizes, int n_in,
                              void* d_out, int out_size, void* d_ws, size_t ws_size,
                              hipStream_t stream)
{
  const float* x   = (const float*)d_in[0];
  const int*   ei  = (const int*)d_in[1];
  const int* batch = (const int*)d_in[2];
  const float* W1a = (const float*)d_in[3];
  const float* b1a = (const float*)d_in[4];
  const float* W1b = (const float*)d_in[5];
  const float* b1b = (const float*)d_in[6];
  const float* W2a = (const float*)d_in[7];
  const float* b2a = (const float*)d_in[8];
  const float* W2b = (const float*)d_in[9];
  const float* b2b = (const float*)d_in[10];
  const float* Wfc = (const float*)d_in[11];
  const float* bfc = (const float*)d_in[12];
  float* out = (float*)d_out;

  const int* src = ei;           // edge_index[0]
  const int* dst = ei + NE;      // edge_index[1]

  // ws: [ushort] xb | A | H | Wt(4)  then [int/float] sums | cnts | cnt_b(512) | rs(+pad) | es(u16) | arena
  unsigned short* xb = (unsigned short*)d_ws;
  unsigned short* A  = xb + (size_t)NN * DF;
  unsigned short* H  = A + (size_t)NN * DF;
  unsigned short* Wt = H + (size_t)NN * DF;
  float* sums  = (float*)(Wt + (size_t)4 * DF * DF);
  int*   cnts  = (int*)(sums + NG * DF);      // 64
  int*   cnt_b = cnts + 64;                   // 512 (NBK used)
  int*   rs    = cnt_b + 512;                 // NN+1, padded to NN+4
  unsigned short* es = (unsigned short*)(rs + (NN + 4));   // NE u16
  unsigned int* arena = (unsigned int*)(es + NE);          // NBK*ACAP u32 (~4.8 MB)

  unsigned short* Wt1a = Wt;
  unsigned short* Wt1b = Wt + DF * DF;
  unsigned short* Wt2a = Wt + 2 * DF * DF;
  unsigned short* Wt2b = Wt + 3 * DF * DF;

  const int gemm_grid   = (NN + 63) / 64;            // 782
  const int gather_grid = (NN * 64 + 255) / 256;     // 12500

  // ---- prep + CSR build ----
  hipMemsetAsync(sums, 0, (size_t)(NG * DF + 64 + 512) * sizeof(float), stream);
  k_prep_part<<<PREP_GRID + PART_GRID, 256, 0, stream>>>(
      x, xb, W1a, W1b, W2a, W2b, Wt, src, dst, cnt_b, arena);
  k_fine<<<NBK, 256, 0, stream>>>(arena, cnt_b, rs, es);

  // ---- conv1 ----
  k_gather<<<gather_grid, 256, 0, stream>>>(xb, A, rs, es);
  k_gemm2<<<gemm_grid, 256, 0, stream>>>(A, Wt1a, b1a, Wt1b, b1b, A, NN);

  // ---- conv2 ----
  k_gather<<<gather_grid, 256, 0, stream>>>(A, H, rs, es);
  k_gemm2<<<gemm_grid, 256, 0, stream>>>(H, Wt2a, b2a, Wt2b, b2b, H, NN);

  // ---- pool + head ----
  k_pool<<<POOL_GRID, 256, 0, stream>>>(H, batch, sums, cnts);
  k_head<<<(NG * NC + 255) / 256, 256, 0, stream>>>(sums, cnts, Wfc, bfc, out);
}